// Round 3
// baseline (68.578 us; speedup 1.0000x reference)
//
#include <hip/hip_runtime.h>
#include <hip/hip_bf16.h>

#define TT 8
#define NN 1536
#define BB 192

typedef __attribute__((ext_vector_type(8))) short short8;
typedef __attribute__((ext_vector_type(4))) float f32x4;

static __device__ inline short f2bf_bits(float x) {
  __hip_bfloat16 b = __float2bfloat16(x);
  return *reinterpret_cast<short*>(&b);
}
static __device__ inline float sigm(float x) {
  return 1.f / (1.f + __expf(-x));
}
static __device__ inline float tanh_fast(float x) {
  return 2.f / (1.f + __expf(-2.f * x)) - 1.f;
}

// ---------------- fused LSTM encoder + a/d precompute (reg/shfl only) ------
// 64 threads/block = 1 wave = 4 agents (16 lanes each). No LDS, no barriers.
__global__ __launch_bounds__(64) void lstm_ad_kernel(
    const float* __restrict__ traj_rel, const float* __restrict__ obs_traj_pos,
    const float* __restrict__ W_he, const float* __restrict__ b_he,
    const float* __restrict__ W_ih, const float* __restrict__ W_hh,
    const float* __restrict__ b_ih, const float* __restrict__ b_hh,
    const float* __restrict__ W_sp, const float* __restrict__ b_sp,
    const float* __restrict__ W_p1, const float* __restrict__ b_p1,
    float* __restrict__ aMat, float* __restrict__ dMat) {
  const int l = threadIdx.x;       // 0..63
  const int u = l & 15;            // hidden unit
  const int la = l >> 4;           // local agent 0..3
  const int agent = blockIdx.x * 4 + la;
  const int gbase = l & 48;        // lane base of this agent's 16-lane group

  // W_hh fragment: whh[g][k] = W_hh[k][g*16+u]
  float whh[4][16];
  #pragma unroll
  for (int g = 0; g < 4; ++g)
    #pragma unroll
    for (int k = 0; k < 16; ++k)
      whh[g][k] = W_hh[k * 64 + g * 16 + u];

  // folded input-path constants
  float G0[4], G1[4], Cc[4];
  #pragma unroll
  for (int g = 0; g < 4; ++g) {
    float a0 = 0.f, a1 = 0.f, c0 = b_ih[g * 16 + u] + b_hh[g * 16 + u];
    #pragma unroll
    for (int e = 0; e < 16; ++e) {
      float wih = W_ih[e * 64 + g * 16 + u];
      a0 = fmaf(W_he[e], wih, a0);
      a1 = fmaf(W_he[16 + e], wih, a1);
      c0 = fmaf(b_he[e], wih, c0);
    }
    G0[g] = a0; G1[g] = a1; Cc[g] = c0;
  }

  // hoist all timestep inputs out of the serial recurrence
  float r0s[TT], r1s[TT];
  #pragma unroll
  for (int t = 0; t < TT; ++t) {
    r0s[t] = traj_rel[(t * NN + agent) * 2 + 0];
    r1s[t] = traj_rel[(t * NN + agent) * 2 + 1];
  }

  // recurrence — register/shfl only; gate FMA chains split 8+8
  float h = 0.f, c = 0.f;
  #pragma unroll
  for (int t = 0; t < TT; ++t) {
    float ga[4], gb[4];
    #pragma unroll
    for (int g = 0; g < 4; ++g) {
      ga[g] = fmaf(r0s[t], G0[g], fmaf(r1s[t], G1[g], Cc[g]));
      gb[g] = 0.f;
    }
    #pragma unroll
    for (int k = 0; k < 8; ++k) {
      float hk = __shfl(h, gbase + k);
      ga[0] = fmaf(hk, whh[0][k], ga[0]);
      ga[1] = fmaf(hk, whh[1][k], ga[1]);
      ga[2] = fmaf(hk, whh[2][k], ga[2]);
      ga[3] = fmaf(hk, whh[3][k], ga[3]);
    }
    #pragma unroll
    for (int k = 8; k < 16; ++k) {
      float hk = __shfl(h, gbase + k);
      gb[0] = fmaf(hk, whh[0][k], gb[0]);
      gb[1] = fmaf(hk, whh[1][k], gb[1]);
      gb[2] = fmaf(hk, whh[2][k], gb[2]);
      gb[3] = fmaf(hk, whh[3][k], gb[3]);
    }
    float g0 = ga[0] + gb[0];
    float g1 = ga[1] + gb[1];
    float g2 = ga[2] + gb[2];
    float g3 = ga[3] + gb[3];
    float si = sigm(g0), sf = sigm(g1), so = sigm(g3);
    float tg = tanh_fast(g2);
    c = sf * c + si * tg;
    h = so * tanh_fast(c);
  }

  // ---- a/d tail: thread owns column m = l ----
  const int m = l;
  float M0 = 0.f, M1 = 0.f, Cm = b_p1[m];
  #pragma unroll
  for (int e = 0; e < 16; ++e) {
    float wp = W_p1[e * 64 + m];
    M0 = fmaf(W_sp[e], wp, M0);
    M1 = fmaf(W_sp[16 + e], wp, M1);
    Cm = fmaf(b_sp[e], wp, Cm);
  }
  float w1h[16];
  #pragma unroll
  for (int k = 0; k < 16; ++k) w1h[k] = W_p1[(16 + k) * 64 + m];

  #pragma unroll
  for (int q = 0; q < 4; ++q) {
    int j = blockIdx.x * 4 + q;
    float px = obs_traj_pos[((TT - 1) * NN + j) * 2 + 0];
    float py = obs_traj_pos[((TT - 1) * NN + j) * 2 + 1];
    float a = fmaf(px, M0, py * M1);
    float dacc = Cm - a;
    #pragma unroll
    for (int k = 0; k < 16; ++k) {
      float hk = __shfl(h, q * 16 + k);
      dacc = fmaf(hk, w1h[k], dacc);
    }
    aMat[j * 64 + m] = a;
    dMat[j * 64 + m] = dacc;
  }
}

// ---------------- fused pool (MFMA) + fusion MLP: one block per robot ------
// 1024 threads = 16 waves, 6 tiles of 16 pairs each.
__global__ __launch_bounds__(1024) void pool_fusion_kernel(
    const float* __restrict__ aMat, const float* __restrict__ dMat,
    const int* __restrict__ neigh, const int* __restrict__ robot_idx,
    const float* __restrict__ W_p2, const float* __restrict__ b_p2,
    const float* __restrict__ obs_traj_pos,
    const float* __restrict__ r_goal, const float* __restrict__ r_pose,
    const float* __restrict__ action,
    const float* __restrict__ W_emb, const float* __restrict__ b_emb,
    const float* __restrict__ W_fc, const float* __restrict__ b_fc,
    float* __restrict__ out) {
  const int b = blockIdx.x;
  const int i = robot_idx[b];
  const int tid = threadIdx.x;
  const int l = tid & 63;
  const int wave = tid >> 6;     // 0..15
  const int n = l & 15;          // output column (and pair-row for A)
  const int grp = l >> 4;        // 0..3

  __shared__ float maskf_s[NN];
  __shared__ float red_s[16][16];
  __shared__ float fuse[37];

  {
    const int* nrow = neigh + i * NN;
    for (int t = tid; t < NN; t += 1024) maskf_s[t] = nrow[t] > 0 ? 1.f : 0.f;
  }

  float a0[8], a1[8];
  {
    const float* arow = aMat + i * 64;
    #pragma unroll
    for (int e = 0; e < 8; ++e) {
      a0[e] = arow[grp * 8 + e];
      a1[e] = arow[32 + grp * 8 + e];
    }
  }
  short8 bfrag0, bfrag1;
  #pragma unroll
  for (int e = 0; e < 8; ++e) {
    bfrag0[e] = f2bf_bits(W_p2[(grp * 8 + e) * 16 + n]);
    bfrag1[e] = f2bf_bits(W_p2[(32 + grp * 8 + e) * 16 + n]);
  }
  const float b2val = b_p2[n];
  __syncthreads();

  // 96 tiles of 16 pairs, 6 per wave, 1-deep software prefetch
  float pmax = 0.f;
  const int tbase = wave * 6;

  const float4* dp0 = (const float4*)(dMat + (tbase * 16 + n) * 64);
  float4 c00 = dp0[grp * 2 + 0];
  float4 c01 = dp0[grp * 2 + 1];
  float4 c10 = dp0[8 + grp * 2 + 0];
  float4 c11 = dp0[8 + grp * 2 + 1];

  #pragma unroll
  for (int tt = 0; tt < 6; ++tt) {
    const int j0 = (tbase + tt) * 16;
    float4 n00, n01, n10, n11;
    if (tt < 5) {
      const float4* np = (const float4*)(dMat + (j0 + 16 + n) * 64);
      n00 = np[grp * 2 + 0];
      n01 = np[grp * 2 + 1];
      n10 = np[8 + grp * 2 + 0];
      n11 = np[8 + grp * 2 + 1];
    } else {
      n00 = c00; n01 = c01; n10 = c10; n11 = c11;
    }

    short8 af0, af1;
    af0[0] = f2bf_bits(fmaxf(a0[0] + c00.x, 0.f));
    af0[1] = f2bf_bits(fmaxf(a0[1] + c00.y, 0.f));
    af0[2] = f2bf_bits(fmaxf(a0[2] + c00.z, 0.f));
    af0[3] = f2bf_bits(fmaxf(a0[3] + c00.w, 0.f));
    af0[4] = f2bf_bits(fmaxf(a0[4] + c01.x, 0.f));
    af0[5] = f2bf_bits(fmaxf(a0[5] + c01.y, 0.f));
    af0[6] = f2bf_bits(fmaxf(a0[6] + c01.z, 0.f));
    af0[7] = f2bf_bits(fmaxf(a0[7] + c01.w, 0.f));
    af1[0] = f2bf_bits(fmaxf(a1[0] + c10.x, 0.f));
    af1[1] = f2bf_bits(fmaxf(a1[1] + c10.y, 0.f));
    af1[2] = f2bf_bits(fmaxf(a1[2] + c10.z, 0.f));
    af1[3] = f2bf_bits(fmaxf(a1[3] + c10.w, 0.f));
    af1[4] = f2bf_bits(fmaxf(a1[4] + c11.x, 0.f));
    af1[5] = f2bf_bits(fmaxf(a1[5] + c11.y, 0.f));
    af1[6] = f2bf_bits(fmaxf(a1[6] + c11.z, 0.f));
    af1[7] = f2bf_bits(fmaxf(a1[7] + c11.w, 0.f));

    f32x4 acc = {0.f, 0.f, 0.f, 0.f};
    acc = __builtin_amdgcn_mfma_f32_16x16x32_bf16(af0, bfrag0, acc, 0, 0, 0);
    acc = __builtin_amdgcn_mfma_f32_16x16x32_bf16(af1, bfrag1, acc, 0, 0, 0);

    #pragma unroll
    for (int q = 0; q < 4; ++q) {
      float v = fmaxf(acc[q] + b2val, 0.f) * maskf_s[j0 + grp * 4 + q];
      pmax = fmaxf(pmax, v);
    }

    c00 = n00; c01 = n01; c10 = n10; c11 = n11;
  }

  pmax = fmaxf(pmax, __shfl_xor(pmax, 16));
  pmax = fmaxf(pmax, __shfl_xor(pmax, 32));
  if (l < 16) red_s[wave][n] = pmax;
  __syncthreads();

  if (tid < 16) {
    float px = obs_traj_pos[((TT - 1) * NN + i) * 2 + 0];
    float py = obs_traj_pos[((TT - 1) * NN + i) * 2 + 1];
    float s0 = r_goal[b * 2 + 0] - px;
    float s1 = r_goal[b * 2 + 1] - py;
    float s2 = action[b * 2 + 0];
    float s3 = action[b * 2 + 1];
    float v = b_emb[tid];
    v = fmaf(s0, W_emb[tid], v);
    v = fmaf(s1, W_emb[16 + tid], v);
    v = fmaf(s2, W_emb[32 + tid], v);
    v = fmaf(s3, W_emb[48 + tid], v);
    fuse[tid] = fmaxf(v, 0.f);
  } else if (tid < 32) {
    int nn = tid - 16;
    float v = red_s[0][nn];
    #pragma unroll
    for (int w = 1; w < 16; ++w) v = fmaxf(v, red_s[w][nn]);
    fuse[tid] = v;
  } else if (tid < 37) {
    fuse[tid] = r_pose[b * 5 + (tid - 32)];
  }
  __syncthreads();

  if (tid < 256) {
    float acc = b_fc[tid];
    #pragma unroll
    for (int k = 0; k < 37; ++k) acc = fmaf(fuse[k], W_fc[k * 256 + tid], acc);
    out[b * 256 + tid] = fmaxf(acc, 0.f);
  }
}

extern "C" void kernel_launch(void* const* d_in, const int* in_sizes, int n_in,
                              void* d_out, int out_size, void* d_ws, size_t ws_size,
                              hipStream_t stream) {
  const float* obs_traj_pos = (const float*)d_in[0];
  const float* traj_rel     = (const float*)d_in[1];
  const int*   neigh_index  = (const int*)d_in[2];
  const int*   robot_idx    = (const int*)d_in[3];
  const float* r_goal       = (const float*)d_in[4];
  const float* r_pose       = (const float*)d_in[5];
  const float* action       = (const float*)d_in[6];
  const float* W_he = (const float*)d_in[7];
  const float* b_he = (const float*)d_in[8];
  const float* W_ih = (const float*)d_in[9];
  const float* W_hh = (const float*)d_in[10];
  const float* b_ih = (const float*)d_in[11];
  const float* b_hh = (const float*)d_in[12];
  const float* W_sp = (const float*)d_in[13];
  const float* b_sp = (const float*)d_in[14];
  const float* W_p1 = (const float*)d_in[15];
  const float* b_p1 = (const float*)d_in[16];
  const float* W_p2 = (const float*)d_in[17];
  const float* b_p2 = (const float*)d_in[18];
  const float* W_emb = (const float*)d_in[19];
  const float* b_emb = (const float*)d_in[20];
  const float* W_fc  = (const float*)d_in[21];
  const float* b_fc  = (const float*)d_in[22];
  float* out = (float*)d_out;

  float* ws = (float*)d_ws;
  float* aMat = ws;              // N*64
  float* dMat = ws + 98304;      // N*64

  lstm_ad_kernel<<<NN / 4, 64, 0, stream>>>(
      traj_rel, obs_traj_pos, W_he, b_he, W_ih, W_hh, b_ih, b_hh,
      W_sp, b_sp, W_p1, b_p1, aMat, dMat);
  // MEASUREMENT PROBE: pool_fusion_kernel is a pure, idempotent function of
  // (aMat, dMat, inputs) -> out. Launch it 4x; b2 = (dur_us - 25.98) / 3.
  // Decision table (committed pre-run):
  //   dur ~33-38  -> kernels tiny, ~20us harness floor dominates -> roofline
  //   dur ~55-65  -> k2 is 10+us -> attack dMat traffic (j-tiled / bf16)
  for (int rep = 0; rep < 4; ++rep) {
    pool_fusion_kernel<<<BB, 1024, 0, stream>>>(
        aMat, dMat, neigh_index, robot_idx, W_p2, b_p2,
        obs_traj_pos, r_goal, r_pose, action, W_emb, b_emb, W_fc, b_fc, out);
  }
}

// Round 4
// 19.301 us; speedup vs baseline: 3.5530x; 3.5530x over previous
//
#include <hip/hip_runtime.h>
#include <hip/hip_bf16.h>

#define TT 8
#define NN 1536
#define BB 192

typedef __attribute__((ext_vector_type(8))) short short8;
typedef __attribute__((ext_vector_type(4))) float f32x4;

static __device__ inline short f2bf_bits(float x) {
  __hip_bfloat16 b = __float2bfloat16(x);
  return *reinterpret_cast<short*>(&b);
}
static __device__ inline float sigm(float x) {
  return 1.f / (1.f + __expf(-x));
}
static __device__ inline float tanh_fast(float x) {
  return 2.f / (1.f + __expf(-2.f * x)) - 1.f;
}

// ---------------- k_a: j-tile pairwise partial-pool ------------------------
// 192 blocks = (96 j-tiles x 2 robot-halves) x 512 threads (8 waves).
// Waves 0-3: LSTM for the tile's 16 agents -> d rows in LDS (no global dMat).
// Waves 4-7 (concurrent): a-rows for 96 robots + neighbor mask -> LDS.
// After one barrier: each wave does 12 robots x (16 j x 64 K x 16 out) via
// 2 MFMAs, masked max over the tile's 16 j's -> part[jt][robot][16].
__global__ __launch_bounds__(512) void pair_partial_kernel(
    const float* __restrict__ traj_rel, const float* __restrict__ obs_traj_pos,
    const float* __restrict__ W_he, const float* __restrict__ b_he,
    const float* __restrict__ W_ih, const float* __restrict__ W_hh,
    const float* __restrict__ b_ih, const float* __restrict__ b_hh,
    const float* __restrict__ W_sp, const float* __restrict__ b_sp,
    const float* __restrict__ W_p1, const float* __restrict__ b_p1,
    const int* __restrict__ neigh, const int* __restrict__ robot_idx,
    const float* __restrict__ W_p2, const float* __restrict__ b_p2,
    float* __restrict__ part) {
  const int jt = blockIdx.x >> 1;
  const int half = blockIdx.x & 1;
  const int j0 = jt * 16;
  const int r0 = half * 96;
  const int tid = threadIdx.x;
  const int wave = tid >> 6;     // 0..7
  const int l = tid & 63;
  const int n = l & 15;
  const int grp = l >> 4;        // 0..3

  __shared__ float dS[16][68];    // +4 pad: break 256B row stride
  __shared__ float aS[96][64];
  __shared__ float maskS[96][16];

  if (wave < 4) {
    // ---- LSTM for agents j0 + wave*4 .. +3 (folded math, reg/shfl only) ----
    const int u = n;             // hidden unit
    const int agent = j0 + wave * 4 + grp;
    const int gbase = l & 48;

    float whh[4][16];
    #pragma unroll
    for (int g = 0; g < 4; ++g)
      #pragma unroll
      for (int k = 0; k < 16; ++k)
        whh[g][k] = W_hh[k * 64 + g * 16 + u];

    float G0[4], G1[4], Cc[4];
    #pragma unroll
    for (int g = 0; g < 4; ++g) {
      float a0 = 0.f, a1 = 0.f, c0 = b_ih[g * 16 + u] + b_hh[g * 16 + u];
      #pragma unroll
      for (int e = 0; e < 16; ++e) {
        float wih = W_ih[e * 64 + g * 16 + u];
        a0 = fmaf(W_he[e], wih, a0);
        a1 = fmaf(W_he[16 + e], wih, a1);
        c0 = fmaf(b_he[e], wih, c0);
      }
      G0[g] = a0; G1[g] = a1; Cc[g] = c0;
    }

    float r0s[TT], r1s[TT];
    #pragma unroll
    for (int t = 0; t < TT; ++t) {
      r0s[t] = traj_rel[(t * NN + agent) * 2 + 0];
      r1s[t] = traj_rel[(t * NN + agent) * 2 + 1];
    }

    float h = 0.f, c = 0.f;
    #pragma unroll
    for (int t = 0; t < TT; ++t) {
      float ga[4], gb[4];
      #pragma unroll
      for (int g = 0; g < 4; ++g) {
        ga[g] = fmaf(r0s[t], G0[g], fmaf(r1s[t], G1[g], Cc[g]));
        gb[g] = 0.f;
      }
      #pragma unroll
      for (int k = 0; k < 8; ++k) {
        float hk = __shfl(h, gbase + k);
        ga[0] = fmaf(hk, whh[0][k], ga[0]);
        ga[1] = fmaf(hk, whh[1][k], ga[1]);
        ga[2] = fmaf(hk, whh[2][k], ga[2]);
        ga[3] = fmaf(hk, whh[3][k], ga[3]);
      }
      #pragma unroll
      for (int k = 8; k < 16; ++k) {
        float hk = __shfl(h, gbase + k);
        gb[0] = fmaf(hk, whh[0][k], gb[0]);
        gb[1] = fmaf(hk, whh[1][k], gb[1]);
        gb[2] = fmaf(hk, whh[2][k], gb[2]);
        gb[3] = fmaf(hk, whh[3][k], gb[3]);
      }
      float g0 = ga[0] + gb[0];
      float g1 = ga[1] + gb[1];
      float g2 = ga[2] + gb[2];
      float g3 = ga[3] + gb[3];
      float si = sigm(g0), sf = sigm(g1), so = sigm(g3);
      float tg = tanh_fast(g2);
      c = sf * c + si * tg;
      h = so * tanh_fast(c);
    }

    // ---- d tail: thread owns column m = l, wave's 4 agents -> dS ----
    const int m = l;
    float M0 = 0.f, M1 = 0.f, Cm = b_p1[m];
    #pragma unroll
    for (int e = 0; e < 16; ++e) {
      float wp = W_p1[e * 64 + m];
      M0 = fmaf(W_sp[e], wp, M0);
      M1 = fmaf(W_sp[16 + e], wp, M1);
      Cm = fmaf(b_sp[e], wp, Cm);
    }
    float w1h[16];
    #pragma unroll
    for (int k = 0; k < 16; ++k) w1h[k] = W_p1[(16 + k) * 64 + m];

    #pragma unroll
    for (int q = 0; q < 4; ++q) {
      int j = j0 + wave * 4 + q;
      float px = obs_traj_pos[((TT - 1) * NN + j) * 2 + 0];
      float py = obs_traj_pos[((TT - 1) * NN + j) * 2 + 1];
      float a = fmaf(px, M0, py * M1);
      float dacc = Cm - a;
      #pragma unroll
      for (int k = 0; k < 16; ++k) {
        float hk = __shfl(h, q * 16 + k);
        dacc = fmaf(hk, w1h[k], dacc);
      }
      dS[wave * 4 + q][m] = dacc;
    }
  } else {
    // ---- concurrent: a-rows + mask for this half's 96 robots ----
    const int w = wave - 4;      // 0..3
    float M0 = 0.f, M1 = 0.f;
    #pragma unroll
    for (int e = 0; e < 16; ++e) {
      float wp = W_p1[e * 64 + l];
      M0 = fmaf(W_sp[e], wp, M0);
      M1 = fmaf(W_sp[16 + e], wp, M1);
    }
    #pragma unroll
    for (int p = 0; p < 24; ++p) {
      int rr = w * 24 + p;
      int ir = robot_idx[r0 + rr];
      float px = obs_traj_pos[((TT - 1) * NN + ir) * 2 + 0];
      float py = obs_traj_pos[((TT - 1) * NN + ir) * 2 + 1];
      aS[rr][l] = fmaf(px, M0, py * M1);
    }
    #pragma unroll
    for (int p = 0; p < 6; ++p) {
      int rr = w * 24 + p * 4 + grp;
      int ir = robot_idx[r0 + rr];
      maskS[rr][n] = (neigh[ir * NN + j0 + n] > 0) ? 1.f : 0.f;
    }
  }

  // every wave: W_p2 fragments (lane-dependent, phase-independent)
  short8 bfrag0, bfrag1;
  #pragma unroll
  for (int e = 0; e < 8; ++e) {
    bfrag0[e] = f2bf_bits(W_p2[(grp * 8 + e) * 16 + n]);
    bfrag1[e] = f2bf_bits(W_p2[(32 + grp * 8 + e) * 16 + n]);
  }
  const float b2val = b_p2[n];
  __syncthreads();

  // d fragment for this lane's pair-row n (robot-invariant, hoisted)
  float d0[8], d1[8];
  #pragma unroll
  for (int e = 0; e < 8; ++e) {
    d0[e] = dS[n][grp * 8 + e];
    d1[e] = dS[n][32 + grp * 8 + e];
  }

  // ---- pairwise: 12 robots per wave ----
  for (int p = 0; p < 12; ++p) {
    const int rr = wave * 12 + p;
    float ar0[8], ar1[8];        // LDS broadcast (same addr per 16-lane grp)
    #pragma unroll
    for (int e = 0; e < 8; ++e) {
      ar0[e] = aS[rr][grp * 8 + e];
      ar1[e] = aS[rr][32 + grp * 8 + e];
    }
    short8 af0, af1;
    #pragma unroll
    for (int e = 0; e < 8; ++e) {
      af0[e] = f2bf_bits(fmaxf(ar0[e] + d0[e], 0.f));
      af1[e] = f2bf_bits(fmaxf(ar1[e] + d1[e], 0.f));
    }
    f32x4 acc = {0.f, 0.f, 0.f, 0.f};
    acc = __builtin_amdgcn_mfma_f32_16x16x32_bf16(af0, bfrag0, acc, 0, 0, 0);
    acc = __builtin_amdgcn_mfma_f32_16x16x32_bf16(af1, bfrag1, acc, 0, 0, 0);

    float vr = 0.f;
    #pragma unroll
    for (int q = 0; q < 4; ++q) {
      float v = fmaxf(acc[q] + b2val, 0.f) * maskS[rr][grp * 4 + q];
      vr = fmaxf(vr, v);
    }
    vr = fmaxf(vr, __shfl_xor(vr, 16));
    vr = fmaxf(vr, __shfl_xor(vr, 32));
    if (l < 16) part[(jt * 192 + r0 + rr) * 16 + n] = vr;
  }
}

// ---------------- k_b: 96-way max reduce + fusion MLP ----------------------
// 192 blocks x 256 threads.
__global__ __launch_bounds__(256) void reduce_fusion_kernel(
    const float* __restrict__ part,
    const int* __restrict__ robot_idx,
    const float* __restrict__ obs_traj_pos,
    const float* __restrict__ r_goal, const float* __restrict__ r_pose,
    const float* __restrict__ action,
    const float* __restrict__ W_emb, const float* __restrict__ b_emb,
    const float* __restrict__ W_fc, const float* __restrict__ b_fc,
    float* __restrict__ out) {
  const int b = blockIdx.x;
  const int tid = threadIdx.x;

  __shared__ float redB[16][16];
  __shared__ float fuse[37];

  {
    const int m = tid & 15;
    const int ch = tid >> 4;     // 0..15
    float v = 0.f;
    #pragma unroll
    for (int s = 0; s < 6; ++s) {
      int jtt = ch + s * 16;     // covers 0..95
      v = fmaxf(v, part[(jtt * 192 + b) * 16 + m]);
    }
    redB[ch][m] = v;
  }
  __syncthreads();

  if (tid < 16) {
    int i = robot_idx[b];
    float px = obs_traj_pos[((TT - 1) * NN + i) * 2 + 0];
    float py = obs_traj_pos[((TT - 1) * NN + i) * 2 + 1];
    float s0 = r_goal[b * 2 + 0] - px;
    float s1 = r_goal[b * 2 + 1] - py;
    float s2 = action[b * 2 + 0];
    float s3 = action[b * 2 + 1];
    float v = b_emb[tid];
    v = fmaf(s0, W_emb[tid], v);
    v = fmaf(s1, W_emb[16 + tid], v);
    v = fmaf(s2, W_emb[32 + tid], v);
    v = fmaf(s3, W_emb[48 + tid], v);
    fuse[tid] = fmaxf(v, 0.f);
  } else if (tid < 32) {
    int m2 = tid - 16;
    float v = redB[0][m2];
    #pragma unroll
    for (int ch = 1; ch < 16; ++ch) v = fmaxf(v, redB[ch][m2]);
    fuse[tid] = v;
  } else if (tid < 37) {
    fuse[tid] = r_pose[b * 5 + (tid - 32)];
  }
  __syncthreads();

  float acc = b_fc[tid];
  #pragma unroll
  for (int k = 0; k < 37; ++k) acc = fmaf(fuse[k], W_fc[k * 256 + tid], acc);
  out[b * 256 + tid] = fmaxf(acc, 0.f);
}

extern "C" void kernel_launch(void* const* d_in, const int* in_sizes, int n_in,
                              void* d_out, int out_size, void* d_ws, size_t ws_size,
                              hipStream_t stream) {
  const float* obs_traj_pos = (const float*)d_in[0];
  const float* traj_rel     = (const float*)d_in[1];
  const int*   neigh_index  = (const int*)d_in[2];
  const int*   robot_idx    = (const int*)d_in[3];
  const float* r_goal       = (const float*)d_in[4];
  const float* r_pose       = (const float*)d_in[5];
  const float* action       = (const float*)d_in[6];
  const float* W_he = (const float*)d_in[7];
  const float* b_he = (const float*)d_in[8];
  const float* W_ih = (const float*)d_in[9];
  const float* W_hh = (const float*)d_in[10];
  const float* b_ih = (const float*)d_in[11];
  const float* b_hh = (const float*)d_in[12];
  const float* W_sp = (const float*)d_in[13];
  const float* b_sp = (const float*)d_in[14];
  const float* W_p1 = (const float*)d_in[15];
  const float* b_p1 = (const float*)d_in[16];
  const float* W_p2 = (const float*)d_in[17];
  const float* b_p2 = (const float*)d_in[18];
  const float* W_emb = (const float*)d_in[19];
  const float* b_emb = (const float*)d_in[20];
  const float* W_fc  = (const float*)d_in[21];
  const float* b_fc  = (const float*)d_in[22];
  float* out = (float*)d_out;

  // part[96][192][16] floats = 1.18 MB; fully overwritten every launch
  // (no zero-init needed -> poison-safe).
  float* part = (float*)d_ws;

  pair_partial_kernel<<<192, 512, 0, stream>>>(
      traj_rel, obs_traj_pos, W_he, b_he, W_ih, W_hh, b_ih, b_hh,
      W_sp, b_sp, W_p1, b_p1, neigh_index, robot_idx, W_p2, b_p2, part);
  reduce_fusion_kernel<<<BB, 256, 0, stream>>>(
      part, robot_idx, obs_traj_pos, r_goal, r_pose, action,
      W_emb, b_emb, W_fc, b_fc, out);
}